// Round 9
// baseline (147.359 us; speedup 1.0000x reference)
//
#include <hip/hip_runtime.h>

// PolynomialAttn: B=2,H=16,S=2048,D=64, degree=2, eps=1e-4, fp32 in/out.
// v9: v8 (2 Q-strips/wave, barrier-free fragment streams) + prefetch depth 2
// (4 rotating reg buffer sets, unroll-4 => compile-time buffer indices) +
// clean induction (peeled tail, no &31 wrap => strength-reduced addressing).

#define S_LEN 2048
#define DH    64
#define BQ    128
#define BK    64
#define EPSTR 68        // epilogue fp32 stride
#define PSTR  65        // prepass V-transpose LDS stride
#define BH_N  32        // B*H
#define PER_BH (S_LEN * DH)   // 131072 elems
#define NT    (S_LEN / BK)    // 32 KV tiles

typedef __bf16 bf16x8 __attribute__((ext_vector_type(8)));
typedef __bf16 bf16x2 __attribute__((ext_vector_type(2)));
typedef float  f32x2  __attribute__((ext_vector_type(2)));
typedef float  f32x4  __attribute__((ext_vector_type(4)));
typedef float  f32x16 __attribute__((ext_vector_type(16)));
typedef unsigned int uivec2 __attribute__((ext_vector_type(2)));

__device__ __forceinline__ unsigned short f2bf(float f) {
    union { float f; unsigned int u; } x; x.f = f;
    unsigned int u = x.u;
    return (unsigned short)((u + 0x7fffu + ((u >> 16) & 1u)) >> 16);  // RNE
}

__device__ __forceinline__ unsigned int pack2bf(float lo, float hi) {
#if __has_builtin(__builtin_amdgcn_cvt_pk_bf16_f32)
    bf16x2 p = __builtin_amdgcn_cvt_pk_bf16_f32(lo, hi);
    union { bf16x2 v; unsigned int u; } c; c.v = p;
    return c.u;
#else
    return (unsigned int)f2bf(lo) | ((unsigned int)f2bf(hi) << 16);
#endif
}

__device__ __forceinline__ void pl32swap(unsigned int& a, unsigned int& b) {
#if __has_builtin(__builtin_amdgcn_permlane32_swap)
    uivec2 r = __builtin_amdgcn_permlane32_swap(a, b, false, false);
    a = r[0]; b = r[1];
#else
    asm("v_permlane32_swap_b32 %0, %1" : "+v"(a), "+v"(b));
#endif
}

// ---------------- prepass: K -> fragment-order bf16, V -> V^T fragment-order bf16 ----
// Kf layout (ushorts): [bh][t][e][ks][lane]*8 ; lane(l31,h) holds
//   K[bh][64t + 32e + l31][16ks + 8h + 0..7]
// Vf layout (ushorts): [bh][t][e][ksl][mt][lane]*8 ; lane(l31,h) holds
//   V^T[bh][mt*32 + l31][64t + 32e + 16ksl + 8h + 0..7]
__global__ __launch_bounds__(256)
void prepass_kernel(const float* __restrict__ kg, const float* __restrict__ vg,
                    unsigned short* __restrict__ kfo, unsigned short* __restrict__ vfo)
{
    __shared__ unsigned short Lk[64 * 72];
    __shared__ unsigned short Lv[64 * PSTR];
    const int tid = threadIdx.x;
    const int bh  = blockIdx.y;
    const int t   = blockIdx.x;
    const size_t base = (size_t)bh * PER_BH + (size_t)t * 64 * DH;

    const float4* kf4 = (const float4*)(kg + base);
    const float4* vf4 = (const float4*)(vg + base);
    #pragma unroll
    for (int r = 0; r < 4; ++r) {
        int idx = r * 256 + tid;              // float4 index in 64x64 tile
        int row = idx >> 4, c4 = idx & 15;
        float4 f = kf4[idx];
        ushort4 hh;
        hh.x = f2bf(f.x); hh.y = f2bf(f.y); hh.z = f2bf(f.z); hh.w = f2bf(f.w);
        *(ushort4*)&Lk[row * 72 + c4 * 4] = hh;
        float4 g = vf4[idx];
        unsigned short* pv = &Lv[row * PSTR + c4 * 4];
        pv[0] = f2bf(g.x); pv[1] = f2bf(g.y); pv[2] = f2bf(g.z); pv[3] = f2bf(g.w);
    }
    __syncthreads();

    unsigned short* kout = kfo + (size_t)bh * PER_BH + (size_t)t * 4096;
    #pragma unroll
    for (int r = 0; r < 2; ++r) {
        int pos = r * 256 + tid;
        int lam = pos & 63, rest = pos >> 6;
        int e = rest >> 2, ks = rest & 3;
        int l31 = lam & 31, h = lam >> 5;
        uint4 v = *(const uint4*)&Lk[(e * 32 + l31) * 72 + ks * 16 + h * 8];
        *(uint4*)(kout + (size_t)pos * 8) = v;
    }
    unsigned short* vout = vfo + (size_t)bh * PER_BH + (size_t)t * 4096;
    #pragma unroll
    for (int r = 0; r < 2; ++r) {
        int pos = r * 256 + tid;
        int lam = pos & 63, rest = pos >> 6;
        int e = rest >> 2, ksl = (rest >> 1) & 1, mt = rest & 1;
        int l31 = lam & 31, h = lam >> 5;
        int d  = mt * 32 + l31;
        int j0 = e * 32 + ksl * 16 + h * 8;
        union { unsigned short s[8]; uint4 u; } u;
        #pragma unroll
        for (int jj = 0; jj < 8; ++jj) u.s[jj] = Lv[(j0 + jj) * PSTR + d];
        *(uint4*)(vout + (size_t)pos * 8) = u.u;
    }
}

// ---------------- main kernel: 2 Q-strips/wave, depth-2 prefetch, no LDS/barriers in loop ----
__global__ __launch_bounds__(256, 2)
void poly_attn_main(const float* __restrict__ qg,
                    const unsigned short* __restrict__ kfo,
                    const unsigned short* __restrict__ vfo,
                    float* __restrict__ og)
{
    __shared__ float epb[8 * 32 * EPSTR];   // per (wave,strip) O^T partials
    __shared__ float dbuf[256];             // per (wave,strip) denominator partials

    const int tid  = threadIdx.x;
    const int lane = tid & 63;
    const int w    = tid >> 6;
    const int p    = w >> 1;      // pair id: Q rows [64p, 64p+64)
    const int e    = w & 1;       // j-half of each KV tile
    const int l31  = lane & 31;
    const int h    = lane >> 5;

    // XCD swizzle: id%8 -> XCD; 4 bh per XCD (K+V 2MB working set in its L2)
    const int id = blockIdx.x;
    const int r5 = id & 31;
    const int bh = (r5 & 7) * 4 + (r5 >> 3);
    const int qt = id >> 5;
    const int q0 = qt * BQ;

    const float* qb = qg + ((size_t)bh * S_LEN + q0) * DH;
    const unsigned short* kw = kfo + (size_t)bh * PER_BH + e * 2048 + (size_t)lane * 8;
    const unsigned short* vw = vfo + (size_t)bh * PER_BH + e * 2048 + (size_t)lane * 8;
    float* ob = og + ((size_t)bh * S_LEN + q0) * DH;

    // ---- Q B-fragments: strip s rows 64p + 32s + l31, cols 16ks + 8h + 0..7 ----
    bf16x8 qfrag[2][4];
    #pragma unroll
    for (int s = 0; s < 2; ++s) {
        #pragma unroll
        for (int ks = 0; ks < 4; ++ks) {
            const float* qp = qb + (64 * p + 32 * s + l31) * DH + ks * 16 + h * 8;
            float4 f0 = *(const float4*)qp;
            float4 f1 = *(const float4*)(qp + 4);
            union { unsigned int d[4]; bf16x8 v; } u;
            u.d[0] = pack2bf(f0.x, f0.y);
            u.d[1] = pack2bf(f0.z, f0.w);
            u.d[2] = pack2bf(f1.x, f1.y);
            u.d[3] = pack2bf(f1.z, f1.w);
            qfrag[s][ks] = u.v;
        }
    }

    f32x16 oacc[2][2];   // [strip][mt]: O^T[d=mt*32+(r&3)+8(r>>2)+4h][i=l31] j-half partial
    #pragma unroll
    for (int s = 0; s < 2; ++s)
        #pragma unroll
        for (int mt = 0; mt < 2; ++mt)
            #pragma unroll
            for (int r = 0; r < 16; ++r) oacc[s][mt][r] = 0.f;
    f32x2 ds2[2];
    ds2[0][0]=0.f; ds2[0][1]=0.f; ds2[1][0]=0.f; ds2[1][1]=0.f;

    // ---- 4 rotating register buffer sets; prefetch depth 2 tiles ----
    uint4 kbuf[4][4], vbuf[4][4];
    #pragma unroll
    for (int x = 0; x < 4; ++x) {
        kbuf[0][x] = *(const uint4*)(kw + x * 512);
        vbuf[0][x] = *(const uint4*)(vw + x * 512);
    }
    #pragma unroll
    for (int x = 0; x < 4; ++x) {
        kbuf[1][x] = *(const uint4*)(kw + 4096 + x * 512);
        vbuf[1][x] = *(const uint4*)(vw + 4096 + x * 512);
    }

    // TILE_BODY(T, CI, PI, DO_PF): consume buffer CI for tile T; if DO_PF,
    // prefetch tile T+2 into buffer PI. All CI/PI compile-time after unroll.
#define TILE_BODY(T, CI, PI, DO_PF)                                                 \
    {                                                                               \
        if (DO_PF) {                                                                \
            const unsigned short* kn_ = kw + (size_t)((T) + 2) * 4096;              \
            const unsigned short* vn_ = vw + (size_t)((T) + 2) * 4096;              \
            _Pragma("unroll")                                                       \
            for (int x = 0; x < 4; ++x) {                                           \
                kbuf[PI][x] = *(const uint4*)(kn_ + x * 512);                       \
                vbuf[PI][x] = *(const uint4*)(vn_ + x * 512);                       \
            }                                                                       \
        }                                                                           \
        f32x16 acc0, acc1;                                                          \
        _Pragma("unroll")                                                           \
        for (int r = 0; r < 16; ++r) { acc0[r] = 0.f; acc1[r] = 0.f; }              \
        _Pragma("unroll")                                                           \
        for (int ks = 0; ks < 4; ++ks) {                                            \
            union { uint4 u; bf16x8 v; } kc; kc.u = kbuf[CI][ks];                   \
            acc0 = __builtin_amdgcn_mfma_f32_32x32x16_bf16(kc.v, qfrag[0][ks], acc0, 0, 0, 0); \
            acc1 = __builtin_amdgcn_mfma_f32_32x32x16_bf16(kc.v, qfrag[1][ks], acc1, 0, 0, 0); \
        }                                                                           \
        _Pragma("unroll")                                                           \
        for (int s = 0; s < 2; ++s) {                                               \
            unsigned int pk[4][2];                                                  \
            _Pragma("unroll")                                                       \
            for (int g = 0; g < 4; ++g) {                                           \
                f32x2 v01, v23;                                                     \
                v01[0] = (s ? acc1 : acc0)[4*g+0]; v01[1] = (s ? acc1 : acc0)[4*g+1]; \
                v23[0] = (s ? acc1 : acc0)[4*g+2]; v23[1] = (s ? acc1 : acc0)[4*g+3]; \
                v01 = v01 * v01; v23 = v23 * v23;                                   \
                ds2[s] += v01; ds2[s] += v23;                                       \
                pk[g][0] = pack2bf(v01[0], v01[1]);                                 \
                pk[g][1] = pack2bf(v23[0], v23[1]);                                 \
            }                                                                       \
            _Pragma("unroll")                                                       \
            for (int ksl = 0; ksl < 2; ++ksl) {                                     \
                unsigned int a0 = pk[2*ksl][0], b0 = pk[2*ksl+1][0];                \
                unsigned int a1 = pk[2*ksl][1], b1 = pk[2*ksl+1][1];                \
                pl32swap(a0, b0);                                                   \
                pl32swap(a1, b1);                                                   \
                union { unsigned int d[4]; bf16x8 v; } bu;                          \
                bu.d[0] = a0; bu.d[1] = a1; bu.d[2] = b0; bu.d[3] = b1;             \
                _Pragma("unroll")                                                   \
                for (int mt = 0; mt < 2; ++mt) {                                    \
                    union { uint4 u; bf16x8 v; } vv; vv.u = vbuf[CI][ksl * 2 + mt]; \
                    oacc[s][mt] = __builtin_amdgcn_mfma_f32_32x32x16_bf16(vv.v, bu.v, oacc[s][mt], 0, 0, 0); \
                }                                                                   \
            }                                                                       \
        }                                                                           \
    }

    for (int tp = 0; tp < NT - 4; tp += 4) {
        TILE_BODY(tp + 0, 0, 2, true);
        TILE_BODY(tp + 1, 1, 3, true);
        TILE_BODY(tp + 2, 2, 0, true);
        TILE_BODY(tp + 3, 3, 1, true);
    }
    // peeled tail (tiles 28..31): only 28,29 still prefetch (30,31)
    TILE_BODY(NT - 4, 0, 2, true);
    TILE_BODY(NT - 3, 1, 3, true);
    TILE_BODY(NT - 2, 2, 0, false);
    TILE_BODY(NT - 1, 3, 1, false);
#undef TILE_BODY

    // ---- denominator partials (column i = l31, this wave's j-half, per strip) ----
    float wavetot[2];
    #pragma unroll
    for (int s = 0; s < 2; ++s) {
        float t = ds2[s][0] + ds2[s][1];
        wavetot[s] = t + __shfl_xor(t, 32);
    }

    // ---- epilogue: stash partials, combine wave-pair j-halves, store ----
    #pragma unroll
    for (int s = 0; s < 2; ++s) {
        float* ep = epb + (size_t)(w * 2 + s) * (32 * EPSTR);
        #pragma unroll
        for (int mt = 0; mt < 2; ++mt) {
            #pragma unroll
            for (int g = 0; g < 4; ++g) {
                f32x4 vv;
                vv[0] = oacc[s][mt][4*g+0];
                vv[1] = oacc[s][mt][4*g+1];
                vv[2] = oacc[s][mt][4*g+2];
                vv[3] = oacc[s][mt][4*g+3];
                // O[i=l31][d = mt*32 + 8g + 4h + 0..3]
                *(f32x4*)&ep[l31 * EPSTR + mt * 32 + 8 * g + 4 * h] = vv;
            }
        }
        if (h == 0) dbuf[(w * 2 + s) * 32 + l31] = wavetot[s];
    }
    __syncthreads();

    // wave w handles output rows [32w, 32w+32): p_src = w>>1, s_src = w&1
    const int psrc = w >> 1, ssrc = w & 1;
    const int r0 = (2 * psrc + 0) * 2 + ssrc;   // e=0 partial region
    const int r1 = (2 * psrc + 1) * 2 + ssrc;   // e=1 partial region
    const int lr = lane >> 1;
    const float den = dbuf[r0 * 32 + lr] + dbuf[r1 * 32 + lr];
    const float inv = 1.0f / fmaxf(den, 1e-4f);
    const float* ea = epb + (size_t)r0 * (32 * EPSTR) + lr * EPSTR;
    const float* eb = epb + (size_t)r1 * (32 * EPSTR) + lr * EPSTR;
    #pragma unroll
    for (int it = 0; it < 8; ++it) {
        int d0 = (lane & 1) * 32 + it * 4;
        f32x4 a = *(const f32x4*)&ea[d0];
        f32x4 b = *(const f32x4*)&eb[d0];
        f32x4 sm;
        sm[0] = (a[0] + b[0]) * inv;
        sm[1] = (a[1] + b[1]) * inv;
        sm[2] = (a[2] + b[2]) * inv;
        sm[3] = (a[3] + b[3]) * inv;
        *(f32x4*)&ob[(32 * w + lr) * DH + d0] = sm;
    }
}

// ---------------- fallback (self-contained, used if ws too small) ----------------
#define LSTR 72
__global__ __launch_bounds__(256, 2)
void poly_attn_fallback(const float* __restrict__ qg, const float* __restrict__ kg,
                        const float* __restrict__ vg, float* __restrict__ og)
{
    __shared__ unsigned short Qs[64 * LSTR];
    __shared__ unsigned short Ksl[64 * LSTR];
    __shared__ unsigned short Vt[64 * LSTR];
    __shared__ unsigned short Xsl[64 * LSTR];

    const int tid  = threadIdx.x;
    const int lane = tid & 63;
    const int w    = tid >> 6;
    const int c    = lane & 15;
    const int quad = lane >> 4;
    const int i0   = w * 16;

    const int bh = blockIdx.y;
    const int q0 = blockIdx.x * 64;

    const float* qb = qg + ((size_t)bh * S_LEN + q0) * DH;
    const float* kb = kg + (size_t)bh * S_LEN * DH;
    const float* vb = vg + (size_t)bh * S_LEN * DH;
    float*       ob = og + ((size_t)bh * S_LEN + q0) * DH;

    {
        const float4* qf4 = (const float4*)qb;
        #pragma unroll
        for (int r = 0; r < 4; ++r) {
            int idx = r * 256 + tid;
            int row = idx >> 4, c4 = idx & 15;
            float4 f = qf4[idx];
            ushort4 hh;
            hh.x = f2bf(f.x); hh.y = f2bf(f.y); hh.z = f2bf(f.z); hh.w = f2bf(f.w);
            *(ushort4*)&Qs[row * LSTR + c4 * 4] = hh;
        }
    }

    f32x4 oacc[4];
    #pragma unroll
    for (int t = 0; t < 4; ++t) { oacc[t][0]=0.f; oacc[t][1]=0.f; oacc[t][2]=0.f; oacc[t][3]=0.f; }
    float dsum[4] = {0.f, 0.f, 0.f, 0.f};

    for (int t0 = 0; t0 < S_LEN; t0 += 64) {
        __syncthreads();
        {
            const float4* kf4 = (const float4*)(kb + (size_t)t0 * DH);
            const float4* vf4 = (const float4*)(vb + (size_t)t0 * DH);
            #pragma unroll
            for (int r = 0; r < 4; ++r) {
                int idx = r * 256 + tid;
                int row = idx >> 4, c4 = idx & 15;
                float4 f = kf4[idx];
                ushort4 hh;
                hh.x = f2bf(f.x); hh.y = f2bf(f.y); hh.z = f2bf(f.z); hh.w = f2bf(f.w);
                *(ushort4*)&Ksl[row * LSTR + c4 * 4] = hh;
                float4 g = vf4[idx];
                int d0 = c4 * 4;
                Vt[(d0 + 0) * LSTR + row] = f2bf(g.x);
                Vt[(d0 + 1) * LSTR + row] = f2bf(g.y);
                Vt[(d0 + 2) * LSTR + row] = f2bf(g.z);
                Vt[(d0 + 3) * LSTR + row] = f2bf(g.w);
            }
        }
        __syncthreads();

        f32x4 xacc[4];
        #pragma unroll
        for (int t = 0; t < 4; ++t) { xacc[t][0]=0.f; xacc[t][1]=0.f; xacc[t][2]=0.f; xacc[t][3]=0.f; }
        #pragma unroll
        for (int k0 = 0; k0 < 64; k0 += 32) {
            bf16x8 af = *(const bf16x8*)&Qs[(i0 + c) * LSTR + k0 + quad * 8];
            #pragma unroll
            for (int tn = 0; tn < 4; ++tn) {
                bf16x8 bfg = *(const bf16x8*)&Ksl[(tn * 16 + c) * LSTR + k0 + quad * 8];
                xacc[tn] = __builtin_amdgcn_mfma_f32_16x16x32_bf16(af, bfg, xacc[tn], 0, 0, 0);
            }
        }
        #pragma unroll
        for (int tn = 0; tn < 4; ++tn)
            #pragma unroll
            for (int r = 0; r < 4; ++r) {
                float xv = xacc[tn][r];
                float xs = xv * xv;
                dsum[r] += xs;
                Xsl[(i0 + quad * 4 + r) * LSTR + tn * 16 + c] = f2bf(xs);
            }
        __syncthreads();

        #pragma unroll
        for (int k0 = 0; k0 < 64; k0 += 32) {
            bf16x8 af = *(const bf16x8*)&Xsl[(i0 + c) * LSTR + k0 + quad * 8];
            #pragma unroll
            for (int tn = 0; tn < 4; ++tn) {
                bf16x8 bfg = *(const bf16x8*)&Vt[(tn * 16 + c) * LSTR + k0 + quad * 8];
                oacc[tn] = __builtin_amdgcn_mfma_f32_16x16x32_bf16(af, bfg, oacc[tn], 0, 0, 0);
            }
        }
    }

    #pragma unroll
    for (int r = 0; r < 4; ++r) {
        float s = dsum[r];
        s += __shfl_xor(s, 1);
        s += __shfl_xor(s, 2);
        s += __shfl_xor(s, 4);
        s += __shfl_xor(s, 8);
        dsum[r] = 1.0f / fmaxf(s, 1e-4f);
    }
    #pragma unroll
    for (int tn = 0; tn < 4; ++tn)
        #pragma unroll
        for (int r = 0; r < 4; ++r)
            ob[(i0 + quad * 4 + r) * DH + tn * 16 + c] = oacc[tn][r] * dsum[r];
}

extern "C" void kernel_launch(void* const* d_in, const int* in_sizes, int n_in,
                              void* d_out, int out_size, void* d_ws, size_t ws_size,
                              hipStream_t stream) {
    (void)in_sizes; (void)n_in; (void)out_size;
    const float* q = (const float*)d_in[0];
    const float* k = (const float*)d_in[1];
    const float* v = (const float*)d_in[2];
    float* o = (float*)d_out;

    const size_t elems = (size_t)BH_N * PER_BH;              // 4,194,304
    const size_t need  = 2 * elems * sizeof(unsigned short); // 16.78 MB

    if (ws_size >= need) {
        unsigned short* kfo = (unsigned short*)d_ws;
        unsigned short* vfo = kfo + elems;
        prepass_kernel<<<dim3(NT, BH_N), 256, 0, stream>>>(k, v, kfo, vfo);
        poly_attn_main<<<dim3(BH_N * S_LEN / BQ), 256, 0, stream>>>(q, kfo, vfo, o);
    } else {
        poly_attn_fallback<<<dim3(S_LEN / 64, BH_N), 256, 0, stream>>>(q, k, v, o);
    }
}

// Round 10
// 133.798 us; speedup vs baseline: 1.1014x; 1.1014x over previous
//
#include <hip/hip_runtime.h>

// PolynomialAttn: B=2,H=16,S=2048,D=64, degree=2, eps=1e-4, fp32 in/out.
// v10: v8 dataflow (2 Q-strips/wave, barrier-free fragment streams, depth-1
// prefetch) + SKEWED PIPELINE: PV lags QK by one tile, so the MFMA pipe
// alternates independent QK(t)/PV(t-1) chains and the transform VALU overlaps
// PV MFMAs. bsave (+16 regs) carries the transformed B-fragments across the
// skew; total regs ~224 < 256 (no v9-style spill).

#define S_LEN 2048
#define DH    64
#define BQ    128
#define BK    64
#define EPSTR 68        // epilogue fp32 stride
#define PSTR  65        // prepass V-transpose LDS stride
#define BH_N  32        // B*H
#define PER_BH (S_LEN * DH)   // 131072 elems
#define NT    (S_LEN / BK)    // 32 KV tiles

typedef __bf16 bf16x8 __attribute__((ext_vector_type(8)));
typedef __bf16 bf16x2 __attribute__((ext_vector_type(2)));
typedef float  f32x2  __attribute__((ext_vector_type(2)));
typedef float  f32x4  __attribute__((ext_vector_type(4)));
typedef float  f32x16 __attribute__((ext_vector_type(16)));
typedef unsigned int uivec2 __attribute__((ext_vector_type(2)));

__device__ __forceinline__ unsigned short f2bf(float f) {
    union { float f; unsigned int u; } x; x.f = f;
    unsigned int u = x.u;
    return (unsigned short)((u + 0x7fffu + ((u >> 16) & 1u)) >> 16);  // RNE
}

__device__ __forceinline__ unsigned int pack2bf(float lo, float hi) {
#if __has_builtin(__builtin_amdgcn_cvt_pk_bf16_f32)
    bf16x2 p = __builtin_amdgcn_cvt_pk_bf16_f32(lo, hi);
    union { bf16x2 v; unsigned int u; } c; c.v = p;
    return c.u;
#else
    return (unsigned int)f2bf(lo) | ((unsigned int)f2bf(hi) << 16);
#endif
}

__device__ __forceinline__ void pl32swap(unsigned int& a, unsigned int& b) {
#if __has_builtin(__builtin_amdgcn_permlane32_swap)
    uivec2 r = __builtin_amdgcn_permlane32_swap(a, b, false, false);
    a = r[0]; b = r[1];
#else
    asm("v_permlane32_swap_b32 %0, %1" : "+v"(a), "+v"(b));
#endif
}

// ---------------- prepass: K -> fragment-order bf16, V -> V^T fragment-order bf16 ----
// Kf layout (ushorts): [bh][t][e][ks][lane]*8 ; lane(l31,h) holds
//   K[bh][64t + 32e + l31][16ks + 8h + 0..7]
// Vf layout (ushorts): [bh][t][e][ksl][mt][lane]*8 ; lane(l31,h) holds
//   V^T[bh][mt*32 + l31][64t + 32e + 16ksl + 8h + 0..7]
__global__ __launch_bounds__(256)
void prepass_kernel(const float* __restrict__ kg, const float* __restrict__ vg,
                    unsigned short* __restrict__ kfo, unsigned short* __restrict__ vfo)
{
    __shared__ unsigned short Lk[64 * 72];
    __shared__ unsigned short Lv[64 * PSTR];
    const int tid = threadIdx.x;
    const int bh  = blockIdx.y;
    const int t   = blockIdx.x;
    const size_t base = (size_t)bh * PER_BH + (size_t)t * 64 * DH;

    const float4* kf4 = (const float4*)(kg + base);
    const float4* vf4 = (const float4*)(vg + base);
    #pragma unroll
    for (int r = 0; r < 4; ++r) {
        int idx = r * 256 + tid;              // float4 index in 64x64 tile
        int row = idx >> 4, c4 = idx & 15;
        float4 f = kf4[idx];
        ushort4 hh;
        hh.x = f2bf(f.x); hh.y = f2bf(f.y); hh.z = f2bf(f.z); hh.w = f2bf(f.w);
        *(ushort4*)&Lk[row * 72 + c4 * 4] = hh;
        float4 g = vf4[idx];
        unsigned short* pv = &Lv[row * PSTR + c4 * 4];
        pv[0] = f2bf(g.x); pv[1] = f2bf(g.y); pv[2] = f2bf(g.z); pv[3] = f2bf(g.w);
    }
    __syncthreads();

    unsigned short* kout = kfo + (size_t)bh * PER_BH + (size_t)t * 4096;
    #pragma unroll
    for (int r = 0; r < 2; ++r) {
        int pos = r * 256 + tid;
        int lam = pos & 63, rest = pos >> 6;
        int e = rest >> 2, ks = rest & 3;
        int l31 = lam & 31, h = lam >> 5;
        uint4 v = *(const uint4*)&Lk[(e * 32 + l31) * 72 + ks * 16 + h * 8];
        *(uint4*)(kout + (size_t)pos * 8) = v;
    }
    unsigned short* vout = vfo + (size_t)bh * PER_BH + (size_t)t * 4096;
    #pragma unroll
    for (int r = 0; r < 2; ++r) {
        int pos = r * 256 + tid;
        int lam = pos & 63, rest = pos >> 6;
        int e = rest >> 2, ksl = (rest >> 1) & 1, mt = rest & 1;
        int l31 = lam & 31, h = lam >> 5;
        int d  = mt * 32 + l31;
        int j0 = e * 32 + ksl * 16 + h * 8;
        union { unsigned short s[8]; uint4 u; } u;
        #pragma unroll
        for (int jj = 0; jj < 8; ++jj) u.s[jj] = Lv[(j0 + jj) * PSTR + d];
        *(uint4*)(vout + (size_t)pos * 8) = u.u;
    }
}

// ---------------- main kernel: skewed QK/PV pipeline, no LDS/barriers in loop ----------------
__global__ __launch_bounds__(256, 2)
void poly_attn_main(const float* __restrict__ qg,
                    const unsigned short* __restrict__ kfo,
                    const unsigned short* __restrict__ vfo,
                    float* __restrict__ og)
{
    __shared__ float epb[8 * 32 * EPSTR];   // per (wave,strip) O^T partials
    __shared__ float dbuf[256];             // per (wave,strip) denominator partials

    const int tid  = threadIdx.x;
    const int lane = tid & 63;
    const int w    = tid >> 6;
    const int p    = w >> 1;      // pair id: Q rows [64p, 64p+64)
    const int e    = w & 1;       // j-half of each KV tile
    const int l31  = lane & 31;
    const int h    = lane >> 5;

    // XCD swizzle: id%8 -> XCD; 4 bh per XCD (K+V 2MB working set in its L2)
    const int id = blockIdx.x;
    const int r5 = id & 31;
    const int bh = (r5 & 7) * 4 + (r5 >> 3);
    const int qt = id >> 5;
    const int q0 = qt * BQ;

    const float* qb = qg + ((size_t)bh * S_LEN + q0) * DH;
    const unsigned short* kw = kfo + (size_t)bh * PER_BH + e * 2048 + (size_t)lane * 8;
    const unsigned short* vw = vfo + (size_t)bh * PER_BH + e * 2048 + (size_t)lane * 8;
    float* ob = og + ((size_t)bh * S_LEN + q0) * DH;

    // ---- Q B-fragments: strip s rows 64p + 32s + l31, cols 16ks + 8h + 0..7 ----
    bf16x8 qfrag[2][4];
    #pragma unroll
    for (int s = 0; s < 2; ++s) {
        #pragma unroll
        for (int ks = 0; ks < 4; ++ks) {
            const float* qp = qb + (64 * p + 32 * s + l31) * DH + ks * 16 + h * 8;
            float4 f0 = *(const float4*)qp;
            float4 f1 = *(const float4*)(qp + 4);
            union { unsigned int d[4]; bf16x8 v; } u;
            u.d[0] = pack2bf(f0.x, f0.y);
            u.d[1] = pack2bf(f0.z, f0.w);
            u.d[2] = pack2bf(f1.x, f1.y);
            u.d[3] = pack2bf(f1.z, f1.w);
            qfrag[s][ks] = u.v;
        }
    }

    f32x16 oacc[2][2];   // [strip][mt]: O^T[d=mt*32+(r&3)+8(r>>2)+4h][i=l31] j-half partial
    #pragma unroll
    for (int s = 0; s < 2; ++s)
        #pragma unroll
        for (int mt = 0; mt < 2; ++mt)
            #pragma unroll
            for (int r = 0; r < 16; ++r) oacc[s][mt][r] = 0.f;
    f32x2 ds2[2];
    ds2[0][0]=0.f; ds2[0][1]=0.f; ds2[1][0]=0.f; ds2[1][1]=0.f;

    uint4 kbuf[2][4], vbuf[2][4];
    unsigned int bsave[2][2][4];   // [strip][ksl][dword] transformed B-frags (skew carry)

    // ---- prologue: k(0)->kbuf0, v(0)->vbuf0, k(1)->kbuf1; QK(0); transform(0) ----
    #pragma unroll
    for (int x = 0; x < 4; ++x) {
        kbuf[0][x] = *(const uint4*)(kw + x * 512);
        vbuf[0][x] = *(const uint4*)(vw + x * 512);
        kbuf[1][x] = *(const uint4*)(kw + 4096 + x * 512);
    }

#define QK_STAGE(KI)                                                                \
        f32x16 acc0, acc1;                                                          \
        _Pragma("unroll")                                                           \
        for (int r = 0; r < 16; ++r) { acc0[r] = 0.f; acc1[r] = 0.f; }              \
        _Pragma("unroll")                                                           \
        for (int ks = 0; ks < 4; ++ks) {                                            \
            union { uint4 u; bf16x8 v; } kc; kc.u = kbuf[KI][ks];                   \
            acc0 = __builtin_amdgcn_mfma_f32_32x32x16_bf16(kc.v, qfrag[0][ks], acc0, 0, 0, 0); \
            acc1 = __builtin_amdgcn_mfma_f32_32x32x16_bf16(kc.v, qfrag[1][ks], acc1, 0, 0, 0); \
        }

#define PV_STAGE(VI)                                                                \
        _Pragma("unroll")                                                           \
        for (int s = 0; s < 2; ++s) {                                               \
            _Pragma("unroll")                                                       \
            for (int ksl = 0; ksl < 2; ++ksl) {                                     \
                union { unsigned int d[4]; bf16x8 v; } bu;                          \
                bu.d[0] = bsave[s][ksl][0]; bu.d[1] = bsave[s][ksl][1];             \
                bu.d[2] = bsave[s][ksl][2]; bu.d[3] = bsave[s][ksl][3];             \
                _Pragma("unroll")                                                   \
                for (int mt = 0; mt < 2; ++mt) {                                    \
                    union { uint4 u; bf16x8 v; } vv; vv.u = vbuf[VI][ksl * 2 + mt]; \
                    oacc[s][mt] = __builtin_amdgcn_mfma_f32_32x32x16_bf16(vv.v, bu.v, oacc[s][mt], 0, 0, 0); \
                }                                                                   \
            }                                                                       \
        }

#define XF_STAGE()                                                                  \
        _Pragma("unroll")                                                           \
        for (int s = 0; s < 2; ++s) {                                               \
            unsigned int pk[4][2];                                                  \
            _Pragma("unroll")                                                       \
            for (int g = 0; g < 4; ++g) {                                           \
                f32x2 v01, v23;                                                     \
                v01[0] = (s ? acc1 : acc0)[4*g+0]; v01[1] = (s ? acc1 : acc0)[4*g+1]; \
                v23[0] = (s ? acc1 : acc0)[4*g+2]; v23[1] = (s ? acc1 : acc0)[4*g+3]; \
                v01 = v01 * v01; v23 = v23 * v23;                                   \
                ds2[s] += v01; ds2[s] += v23;                                       \
                pk[g][0] = pack2bf(v01[0], v01[1]);                                 \
                pk[g][1] = pack2bf(v23[0], v23[1]);                                 \
            }                                                                       \
            _Pragma("unroll")                                                       \
            for (int ksl = 0; ksl < 2; ++ksl) {                                     \
                unsigned int a0 = pk[2*ksl][0], b0 = pk[2*ksl+1][0];                \
                unsigned int a1 = pk[2*ksl][1], b1 = pk[2*ksl+1][1];                \
                pl32swap(a0, b0);                                                   \
                pl32swap(a1, b1);                                                   \
                bsave[s][ksl][0] = a0; bsave[s][ksl][1] = a1;                       \
                bsave[s][ksl][2] = b0; bsave[s][ksl][3] = b1;                       \
            }                                                                       \
        }

    { QK_STAGE(0); XF_STAGE(); }

    // BODY(T): loads k(T+1) [if DO_KPF], v(T); QK(T); PV(T-1); transform(T).
#define BODY(T, KC, KN, VL, VC, DO_KPF)                                             \
    {                                                                               \
        if (DO_KPF) {                                                               \
            const unsigned short* kn_ = kw + (size_t)((T) + 1) * 4096;              \
            _Pragma("unroll")                                                       \
            for (int x = 0; x < 4; ++x) kbuf[KN][x] = *(const uint4*)(kn_ + x * 512); \
        }                                                                           \
        {                                                                           \
            const unsigned short* vn_ = vw + (size_t)(T) * 4096;                    \
            _Pragma("unroll")                                                       \
            for (int x = 0; x < 4; ++x) vbuf[VL][x] = *(const uint4*)(vn_ + x * 512); \
        }                                                                           \
        QK_STAGE(KC);                                                               \
        PV_STAGE(VC);                                                               \
        XF_STAGE();                                                                 \
    }

    for (int tp = 1; tp < NT - 1; tp += 2) {
        BODY(tp,     1, 0, 1, 0, true);
        BODY(tp + 1, 0, 1, 0, 1, true);
    }
    BODY(NT - 1, 1, 0, 1, 0, false);
    { PV_STAGE(1); }   // drain: PV(31)
#undef BODY
#undef QK_STAGE
#undef PV_STAGE
#undef XF_STAGE

    // ---- denominator partials (column i = l31, this wave's j-half, per strip) ----
    float wavetot[2];
    #pragma unroll
    for (int s = 0; s < 2; ++s) {
        float t = ds2[s][0] + ds2[s][1];
        wavetot[s] = t + __shfl_xor(t, 32);
    }

    // ---- epilogue: stash partials, combine wave-pair j-halves, store ----
    #pragma unroll
    for (int s = 0; s < 2; ++s) {
        float* ep = epb + (size_t)(w * 2 + s) * (32 * EPSTR);
        #pragma unroll
        for (int mt = 0; mt < 2; ++mt) {
            #pragma unroll
            for (int g = 0; g < 4; ++g) {
                f32x4 vv;
                vv[0] = oacc[s][mt][4*g+0];
                vv[1] = oacc[s][mt][4*g+1];
                vv[2] = oacc[s][mt][4*g+2];
                vv[3] = oacc[s][mt][4*g+3];
                // O[i=l31][d = mt*32 + 8g + 4h + 0..3]
                *(f32x4*)&ep[l31 * EPSTR + mt * 32 + 8 * g + 4 * h] = vv;
            }
        }
        if (h == 0) dbuf[(w * 2 + s) * 32 + l31] = wavetot[s];
    }
    __syncthreads();

    // wave w handles output rows [32w, 32w+32): p_src = w>>1, s_src = w&1
    const int psrc = w >> 1, ssrc = w & 1;
    const int r0 = (2 * psrc + 0) * 2 + ssrc;   // e=0 partial region
    const int r1 = (2 * psrc + 1) * 2 + ssrc;   // e=1 partial region
    const int lr = lane >> 1;
    const float den = dbuf[r0 * 32 + lr] + dbuf[r1 * 32 + lr];
    const float inv = 1.0f / fmaxf(den, 1e-4f);
    const float* ea = epb + (size_t)r0 * (32 * EPSTR) + lr * EPSTR;
    const float* eb = epb + (size_t)r1 * (32 * EPSTR) + lr * EPSTR;
    #pragma unroll
    for (int it = 0; it < 8; ++it) {
        int d0 = (lane & 1) * 32 + it * 4;
        f32x4 a = *(const f32x4*)&ea[d0];
        f32x4 b = *(const f32x4*)&eb[d0];
        f32x4 sm;
        sm[0] = (a[0] + b[0]) * inv;
        sm[1] = (a[1] + b[1]) * inv;
        sm[2] = (a[2] + b[2]) * inv;
        sm[3] = (a[3] + b[3]) * inv;
        *(f32x4*)&ob[(32 * w + lr) * DH + d0] = sm;
    }
}

// ---------------- fallback (self-contained, used if ws too small) ----------------
#define LSTR 72
__global__ __launch_bounds__(256, 2)
void poly_attn_fallback(const float* __restrict__ qg, const float* __restrict__ kg,
                        const float* __restrict__ vg, float* __restrict__ og)
{
    __shared__ unsigned short Qs[64 * LSTR];
    __shared__ unsigned short Ksl[64 * LSTR];
    __shared__ unsigned short Vt[64 * LSTR];
    __shared__ unsigned short Xsl[64 * LSTR];

    const int tid  = threadIdx.x;
    const int lane = tid & 63;
    const int w    = tid >> 6;
    const int c    = lane & 15;
    const int quad = lane >> 4;
    const int i0   = w * 16;

    const int bh = blockIdx.y;
    const int q0 = blockIdx.x * 64;

    const float* qb = qg + ((size_t)bh * S_LEN + q0) * DH;
    const float* kb = kg + (size_t)bh * S_LEN * DH;
    const float* vb = vg + (size_t)bh * S_LEN * DH;
    float*       ob = og + ((size_t)bh * S_LEN + q0) * DH;

    {
        const float4* qf4 = (const float4*)qb;
        #pragma unroll
        for (int r = 0; r < 4; ++r) {
            int idx = r * 256 + tid;
            int row = idx >> 4, c4 = idx & 15;
            float4 f = qf4[idx];
            ushort4 hh;
            hh.x = f2bf(f.x); hh.y = f2bf(f.y); hh.z = f2bf(f.z); hh.w = f2bf(f.w);
            *(ushort4*)&Qs[row * LSTR + c4 * 4] = hh;
        }
    }

    f32x4 oacc[4];
    #pragma unroll
    for (int t = 0; t < 4; ++t) { oacc[t][0]=0.f; oacc[t][1]=0.f; oacc[t][2]=0.f; oacc[t][3]=0.f; }
    float dsum[4] = {0.f, 0.f, 0.f, 0.f};

    for (int t0 = 0; t0 < S_LEN; t0 += 64) {
        __syncthreads();
        {
            const float4* kf4 = (const float4*)(kb + (size_t)t0 * DH);
            const float4* vf4 = (const float4*)(vb + (size_t)t0 * DH);
            #pragma unroll
            for (int r = 0; r < 4; ++r) {
                int idx = r * 256 + tid;
                int row = idx >> 4, c4 = idx & 15;
                float4 f = kf4[idx];
                ushort4 hh;
                hh.x = f2bf(f.x); hh.y = f2bf(f.y); hh.z = f2bf(f.z); hh.w = f2bf(f.w);
                *(ushort4*)&Ksl[row * LSTR + c4 * 4] = hh;
                float4 g = vf4[idx];
                int d0 = c4 * 4;
                Vt[(d0 + 0) * LSTR + row] = f2bf(g.x);
                Vt[(d0 + 1) * LSTR + row] = f2bf(g.y);
                Vt[(d0 + 2) * LSTR + row] = f2bf(g.z);
                Vt[(d0 + 3) * LSTR + row] = f2bf(g.w);
            }
        }
        __syncthreads();

        f32x4 xacc[4];
        #pragma unroll
        for (int t = 0; t < 4; ++t) { xacc[t][0]=0.f; xacc[t][1]=0.f; xacc[t][2]=0.f; xacc[t][3]=0.f; }
        #pragma unroll
        for (int k0 = 0; k0 < 64; k0 += 32) {
            bf16x8 af = *(const bf16x8*)&Qs[(i0 + c) * LSTR + k0 + quad * 8];
            #pragma unroll
            for (int tn = 0; tn < 4; ++tn) {
                bf16x8 bfg = *(const bf16x8*)&Ksl[(tn * 16 + c) * LSTR + k0 + quad * 8];
                xacc[tn] = __builtin_amdgcn_mfma_f32_16x16x32_bf16(af, bfg, xacc[tn], 0, 0, 0);
            }
        }
        #pragma unroll
        for (int tn = 0; tn < 4; ++tn)
            #pragma unroll
            for (int r = 0; r < 4; ++r) {
                float xv = xacc[tn][r];
                float xs = xv * xv;
                dsum[r] += xs;
                Xsl[(i0 + quad * 4 + r) * LSTR + tn * 16 + c] = f2bf(xs);
            }
        __syncthreads();

        #pragma unroll
        for (int k0 = 0; k0 < 64; k0 += 32) {
            bf16x8 af = *(const bf16x8*)&Xsl[(i0 + c) * LSTR + k0 + quad * 8];
            #pragma unroll
            for (int tn = 0; tn < 4; ++tn) {
                bf16x8 bfg = *(const bf16x8*)&Vt[(tn * 16 + c) * LSTR + k0 + quad * 8];
                oacc[tn] = __builtin_amdgcn_mfma_f32_16x16x32_bf16(af, bfg, oacc[tn], 0, 0, 0);
            }
        }
    }

    #pragma unroll
    for (int r = 0; r < 4; ++r) {
        float s = dsum[r];
        s += __shfl_xor(s, 1);
        s += __shfl_xor(s, 2);
        s += __shfl_xor(s, 4);
        s += __shfl_xor(s, 8);
        dsum[r] = 1.0f / fmaxf(s, 1e-4f);
    }
    #pragma unroll
    for (int tn = 0; tn < 4; ++tn)
        #pragma unroll
        for (int r = 0; r < 4; ++r)
            ob[(i0 + quad * 4 + r) * DH + tn * 16 + c] = oacc[tn][r] * dsum[r];
}

extern "C" void kernel_launch(void* const* d_in, const int* in_sizes, int n_in,
                              void* d_out, int out_size, void* d_ws, size_t ws_size,
                              hipStream_t stream) {
    (void)in_sizes; (void)n_in; (void)out_size;
    const float* q = (const float*)d_in[0];
    const float* k = (const float*)d_in[1];
    const float* v = (const float*)d_in[2];
    float* o = (float*)d_out;

    const size_t elems = (size_t)BH_N * PER_BH;              // 4,194,304
    const size_t need  = 2 * elems * sizeof(unsigned short); // 16.78 MB

    if (ws_size >= need) {
        unsigned short* kfo = (unsigned short*)d_ws;
        unsigned short* vfo = kfo + elems;
        prepass_kernel<<<dim3(NT, BH_N), 256, 0, stream>>>(k, v, kfo, vfo);
        poly_attn_main<<<dim3(BH_N * S_LEN / BQ), 256, 0, stream>>>(q, kfo, vfo, o);
    } else {
        poly_attn_fallback<<<dim3(S_LEN / 64, BH_N), 256, 0, stream>>>(q, k, v, o);
    }
}